// Round 5
// baseline (3979.805 us; speedup 1.0000x reference)
//
#include <hip/hip_runtime.h>
#include <cstdio>
#include <cstdint>

#define B_   128
#define L_   512
#define H_   512
#define IN_  64
#define OUT_ 64
#define NH_  8
#define HD_  64
#define HOR_ 24
#define KCAT 576   // IN_ + H_
#define G4H  2048  // 4*H_

typedef unsigned short u16;
typedef __attribute__((ext_vector_type(8))) __bf16 bf16x8;
typedef __attribute__((ext_vector_type(4))) float f32x4;

__device__ __forceinline__ float bfbits2f(uint32_t hi){ union { uint32_t u; float f; } v; v.u = hi; return v.f; }
__device__ __forceinline__ u16 f2bf(float f){
  union { uint32_t u; float f2; } v; v.f2 = f;
  uint32_t x = v.u;
  return (u16)((x + 0x7FFFu + ((x >> 16) & 1u)) >> 16);  // RNE
}

// ---------------- one-time prep ----------------

__global__ __launch_bounds__(256) void k_convert_x(const float4* __restrict__ X, ushort4* __restrict__ Xb, int n4){
  int i = blockIdx.x * blockDim.x + threadIdx.x;
  int stride = gridDim.x * blockDim.x;
  for (; i < n4; i += stride){
    float4 v = X[i];
    ushort4 o;
    o.x = f2bf(v.x); o.y = f2bf(v.y); o.z = f2bf(v.z); o.w = f2bf(v.w);
    Xb[i] = o;
  }
}

// fused small prep: block ranges
//  [0,129)        Mt (heavy: Wfc@Wo) + bcomb
//  [129,2177)     Wkv bf16 convert
//  [2177,6785)    Wt4 interleaved gate weights
//  [6785,7809)    Wqt transpose
//  [7809,7817)    bias4
//  [7817,8073)    predpart init (nh0 = dec, rest 0)
//  [8073,8329)    hb0 = h0
//  [8329,8585)    cbuf = c0
//  [8585,8586)    zero barrier block
__global__ __launch_bounds__(256) void k_prep(const float* __restrict__ Wk, const float* __restrict__ Wv,
                                              const float* __restrict__ W_ih, const float* __restrict__ W_hh,
                                              const float* __restrict__ b_ih, const float* __restrict__ b_hh,
                                              const float* __restrict__ Wq, const float* __restrict__ Wfc,
                                              const float* __restrict__ Wo, const float* __restrict__ bo,
                                              const float* __restrict__ bfc, const float* __restrict__ dec,
                                              const float* __restrict__ h0, const float* __restrict__ c0,
                                              u16* __restrict__ Wkv, float* __restrict__ Wt4,
                                              float* __restrict__ Wqt, float* __restrict__ bias4,
                                              float* __restrict__ Mt, float* __restrict__ bcomb,
                                              float* __restrict__ predpart, float* __restrict__ hb0,
                                              float* __restrict__ cbuf, uint32_t* __restrict__ bar){
  const int bid = blockIdx.x, tid = threadIdx.x;
  if (bid < 129){
    int i = bid * 256 + tid;
    if (i < 32768){
      int p = i >> 9, d = i & 511;
      float acc = 0.f;
      #pragma unroll 4
      for (int j = 0; j < 512; j++) acc += Wfc[p * 512 + j] * Wo[j * 512 + d];
      Mt[d * 64 + p] = acc;
    } else if (i < 32832){
      int p = i - 32768;
      float acc = bfc[p];
      for (int j = 0; j < 512; j++) acc += Wfc[p * 512 + j] * bo[j];
      bcomb[p] = acc;
    }
  } else if (bid < 2177){
    int i = (bid - 129) * 256 + tid;           // 1024*512
    int n = i >> 9;
    Wkv[i] = f2bf(n < 512 ? Wk[i] : Wv[i - 262144]);
  } else if (bid < 6785){
    int i = (bid - 2177) * 256 + tid;          // 576*2048
    int k = i >> 11, rem = i & 2047;
    int j = rem >> 2, g = rem & 3;
    int row = g * 512 + j;
    Wt4[i] = (k < 64) ? W_ih[row * 64 + k] : W_hh[row * 512 + (k - 64)];
  } else if (bid < 7809){
    int i = (bid - 6785) * 256 + tid;          // 512*512
    int k = i >> 9, n = i & 511;
    Wqt[i] = Wq[n * 512 + k];
  } else if (bid < 7817){
    int i = (bid - 7809) * 256 + tid;          // 2048
    int j = i >> 2, g = i & 3;
    bias4[i] = b_ih[g * 512 + j] + b_hh[g * 512 + j];
  } else if (bid < 8073){
    int i = (bid - 7817) * 256 + tid;          // 128*8*64
    int b = i >> 9, r = i & 511;
    int nh = r >> 6, p = r & 63;
    predpart[i] = (nh == 0) ? dec[b * 64 + p] : 0.f;
  } else if (bid < 8329){
    int i = (bid - 8073) * 256 + tid;          // 128*512
    hb0[i] = h0[i];
  } else if (bid < 8585){
    int i = (bid - 8329) * 256 + tid;          // 128*512
    cbuf[i] = c0[i];
  } else {
    for (int i = tid; i < 1024; i += 256) bar[i] = 0u;
  }
}

// ---------------- phase 1: K/V projection (bf16 MFMA GEMM) ----------------
// XCD-aware remap (FETCH ~39 MB). K written TRANSPOSED: Kt[(b*8+nh)][hd][l];
// V row-major Vb[(b*8+nh)][l][hd].
__global__ __launch_bounds__(256) void k_gemm_kv(const u16* __restrict__ Xb, const u16* __restrict__ Wkv,
                                                 const float* __restrict__ bk, const float* __restrict__ bv,
                                                 u16* __restrict__ Kt, u16* __restrict__ Vb){
  __shared__ __align__(16) u16 As[128 * 64];
  __shared__ __align__(16) u16 Bs[128 * 64];
  const int tid = threadIdx.x;
  const int lane = tid & 63, wid = tid >> 6;
  const int wm = wid >> 1, wn = wid & 1;
  const int lid = blockIdx.x + blockIdx.y * 8;   // gridDim = (8, 512)
  const int xcd = lid & 7;
  const int seq = lid >> 3;
  const int n0 = (seq & 7) * 128;
  const int m0 = ((seq >> 3) + xcd * 64) * 128;

  f32x4 zero = {0.f, 0.f, 0.f, 0.f};
  f32x4 acc[4][4];
  #pragma unroll
  for (int i = 0; i < 4; i++)
    #pragma unroll
    for (int j = 0; j < 4; j++) acc[i][j] = zero;

  for (int kt = 0; kt < 512; kt += 64){
    #pragma unroll
    for (int s = 0; s < 4; s++){
      int slot = tid + 256 * s;                // 0..1023
      int r = slot >> 3, cg = slot & 7;
      int sw = (cg ^ (r & 7)) << 3;
      *(uint4*)&As[r * 64 + sw] = *(const uint4*)&Xb[(size_t)(m0 + r) * 512 + kt + cg * 8];
      *(uint4*)&Bs[r * 64 + sw] = *(const uint4*)&Wkv[(size_t)(n0 + r) * 512 + kt + cg * 8];
    }
    __syncthreads();
    #pragma unroll
    for (int ks = 0; ks < 2; ks++){
      bf16x8 af[4], bfr[4];
      int g = ks * 4 + (lane >> 4);
      int ra = wm * 64 + (lane & 15);
      int rb = wn * 64 + (lane & 15);
      #pragma unroll
      for (int i = 0; i < 4; i++){
        int r = ra + i * 16;
        af[i] = *(const bf16x8*)&As[r * 64 + ((g ^ (r & 7)) << 3)];
      }
      #pragma unroll
      for (int j = 0; j < 4; j++){
        int r = rb + j * 16;
        bfr[j] = *(const bf16x8*)&Bs[r * 64 + ((g ^ (r & 7)) << 3)];
      }
      #pragma unroll
      for (int i = 0; i < 4; i++)
        #pragma unroll
        for (int j = 0; j < 4; j++)
          acc[i][j] = __builtin_amdgcn_mfma_f32_16x16x32_bf16(af[i], bfr[j], acc[i][j], 0, 0, 0);
    }
    __syncthreads();
  }

  #pragma unroll
  for (int j = 0; j < 4; j++){
    int n = n0 + wn * 64 + j * 16 + (lane & 15);
    int nh = (n >> 6) & 7, hd = n & 63;
    if (n < 512){
      float bias = bk[n];
      #pragma unroll
      for (int i = 0; i < 4; i++){
        int mbase = m0 + wm * 64 + i * 16 + (lane >> 4) * 4;
        int b = mbase >> 9, l = mbase & 511;
        ushort4 pk;
        pk.x = f2bf(acc[i][j][0] + bias);
        pk.y = f2bf(acc[i][j][1] + bias);
        pk.z = f2bf(acc[i][j][2] + bias);
        pk.w = f2bf(acc[i][j][3] + bias);
        *(ushort4*)&Kt[((size_t)((b * 8 + nh) * 64 + hd)) * 512 + l] = pk;
      }
    } else {
      float bias = bv[n - 512];
      #pragma unroll
      for (int i = 0; i < 4; i++){
        #pragma unroll
        for (int r = 0; r < 4; r++){
          int m = m0 + wm * 64 + i * 16 + (lane >> 4) * 4 + r;
          int b = m >> 9, l = m & 511;
          Vb[((size_t)((b * 8 + nh) * 512 + l)) * 64 + hd] = f2bf(acc[i][j][r] + bias);
        }
      }
    }
  }
}

// ---------------- persistent 24-step loop, manual grid barrier ----------------
// bar layout (uint32): [g*32] g=0..7 group arrival counters, [256] global, [288] release.

__device__ __forceinline__ void gridbar(uint32_t* bar, int grp, uint32_t phase){
  __syncthreads();
  if (threadIdx.x == 0){
    uint32_t prev = __hip_atomic_fetch_add(&bar[grp * 32], 1u, __ATOMIC_ACQ_REL, __HIP_MEMORY_SCOPE_AGENT);
    if ((prev & 63u) == 63u){
      uint32_t p2 = __hip_atomic_fetch_add(&bar[256], 1u, __ATOMIC_ACQ_REL, __HIP_MEMORY_SCOPE_AGENT);
      if ((p2 & 7u) == 7u)
        __hip_atomic_store(&bar[288], phase, __ATOMIC_RELEASE, __HIP_MEMORY_SCOPE_AGENT);
    }
    while (__hip_atomic_load(&bar[288], __ATOMIC_ACQUIRE, __HIP_MEMORY_SCOPE_AGENT) < phase)
      __builtin_amdgcn_s_sleep(2);
  }
  __syncthreads();
}

struct SharedG { float xs[8][KCAT]; };                    // 18432 B
struct SharedA { float qs[64]; float sc[512]; float red[16];
                 float ctxp[4][64]; float ctxc[64]; float predred[4][64]; };
struct SharedQ { float hq[2][512]; float qp[4][2][64]; };
union SharedU { SharedG g; SharedA a; SharedQ q; };

__global__ __launch_bounds__(256, 2) void k_loop(float* __restrict__ hb0, float* __restrict__ hb1,
                                                 float* __restrict__ cbuf,
                                                 const float4* __restrict__ Wt4, const float4* __restrict__ bias4,
                                                 const float* __restrict__ Wqt, const float* __restrict__ bq,
                                                 const u16* __restrict__ Kt, const u16* __restrict__ Vb,
                                                 const float* __restrict__ Mt, const float* __restrict__ bcomb,
                                                 float* __restrict__ qbuf, float* __restrict__ predpart,
                                                 uint32_t* __restrict__ bar,
                                                 float* __restrict__ out_pred, float* __restrict__ out_attn){
  __shared__ SharedU sh;
  const int bid = blockIdx.x;          // 0..511
  const int tid = threadIdx.x;
  const int lane = tid & 63, wid = tid >> 6;
  const int xcd = bid & 7;             // round-robin dispatch -> XCD id
  const int idx = bid >> 3;            // 0..63 within XCD
  uint32_t ph = 0;

  for (int t = 0; t < HOR_; t++){
    float* hin  = (t & 1) ? hb1 : hb0;
    float* hout = (t & 1) ? hb0 : hb1;

    // ---- phase G: assemble x=[pred,h] in LDS; gates GEMM + LSTM ----
    // tiling: bt=idx>>2 (8 b's), jsub=idx&3; j-slice per XCD = 64 j (L2-resident weights)
    {
      const int bt = idx >> 2, jsub = idx & 3;
      const int b0g = bt * 8;
      const bool wr = (xcd == 0) && (jsub == 0);
      // x part: pred = sum_nh predpart + bcomb (t>0); t=0: predpart holds dec in nh0
      for (int i = tid; i < 512; i += 256){
        int rr = i >> 6, p = i & 63;
        float s = (t == 0) ? 0.f : bcomb[p];
        const float* ppp = &predpart[((size_t)(b0g + rr) * 8) * 64 + p];
        #pragma unroll
        for (int nh2 = 0; nh2 < 8; nh2++) s += ppp[nh2 * 64];
        sh.g.xs[rr][p] = s;
        if (wr && t > 0)
          out_pred[(size_t)(b0g + rr) * (HOR_ * OUT_) + (t - 1) * 64 + p] = s;
      }
      // h part
      for (int i = tid; i < 8 * 512; i += 256){
        int rr = i >> 9, c = i & 511;
        sh.g.xs[rr][64 + c] = hin[(b0g + rr) * 512 + c];
      }
      __syncthreads();
      const int bl = tid >> 5, kh = (tid >> 4) & 1, jl = tid & 15;
      const int j = xcd * 64 + jsub * 16 + jl;         // 0..511
      float4 a = {0.f, 0.f, 0.f, 0.f};
      const float4* W = Wt4 + (size_t)(kh * 288) * 512 + j;
      const float* x = &sh.g.xs[bl][kh * 288];
      #pragma unroll 8
      for (int k = 0; k < 288; k++){
        float xv = x[k];
        float4 w = W[(size_t)k * 512];
        a.x += xv * w.x; a.y += xv * w.y; a.z += xv * w.z; a.w += xv * w.w;
      }
      a.x += __shfl_xor(a.x, 16);
      a.y += __shfl_xor(a.y, 16);
      a.z += __shfl_xor(a.z, 16);
      a.w += __shfl_xor(a.w, 16);
      if (kh == 0){
        float4 bs = bias4[j];
        float ai = a.x + bs.x, af = a.y + bs.y, ag = a.z + bs.z, ao = a.w + bs.w;
        int b = b0g + bl;
        float c_old = cbuf[b * 512 + j];
        float ig = 1.f / (1.f + __expf(-ai));
        float fg = 1.f / (1.f + __expf(-af));
        float e2 = __expf(2.f * ag);
        float gg = 1.f - 2.f / (e2 + 1.f);
        float og = 1.f / (1.f + __expf(-ao));
        float cn = fg * c_old + ig * gg;
        float ec = __expf(2.f * cn);
        float th = 1.f - 2.f / (ec + 1.f);
        cbuf[b * 512 + j] = cn;
        hout[b * 512 + j] = og * th;
      }
    }
    gridbar(bar, xcd, ++ph);

    // ---- phase Q: q = (h@Wq.T+bq)*scale; XCD-pinned n-slice (L2-resident Wqt) ----
    {
      const int b0q = idx * 2;
      const int n0x = xcd * 64;
      for (int i = tid; i < 1024; i += 256){
        int b2 = i >> 9, c = i & 511;
        sh.q.hq[b2][c] = hout[(b0q + b2) * 512 + c];
      }
      __syncthreads();
      const int kp = tid >> 6, nl = tid & 63;
      float a0 = 0.f, a1 = 0.f;
      const float* wp = Wqt + (size_t)(kp * 128) * 512 + n0x + nl;
      const float* h0p = &sh.q.hq[0][kp * 128];
      const float* h1p = &sh.q.hq[1][kp * 128];
      #pragma unroll 8
      for (int k = 0; k < 128; k++){
        float w = wp[(size_t)k * 512];
        a0 += h0p[k] * w;
        a1 += h1p[k] * w;
      }
      sh.q.qp[kp][0][nl] = a0;
      sh.q.qp[kp][1][nl] = a1;
      __syncthreads();
      if (tid < 128){
        int b2 = tid >> 6, nl2 = tid & 63;
        float q = sh.q.qp[0][b2][nl2] + sh.q.qp[1][b2][nl2] + sh.q.qp[2][b2][nl2] + sh.q.qp[3][b2][nl2]
                + bq[n0x + nl2];
        qbuf[(b0q + b2) * 512 + n0x + nl2] = q * 0.125f;
      }
    }
    gridbar(bar, xcd, ++ph);

    // ---- phase A: attention + fused per-head pred partial (2 heads/block) ----
    for (int s = 0; s < 2; s++){
      const int bx = bid * 2 + s;
      const int b = bx >> 3, nh = bx & 7;
      __syncthreads();
      if (tid < 64) sh.a.qs[tid] = qbuf[b * 512 + nh * 64 + tid];
      __syncthreads();

      const u16* Ktp = Kt + (size_t)bx * (64 * 512);
      float s0 = 0.f, s1 = 0.f;
      #pragma unroll 8
      for (int d = 0; d < 64; d++){
        uint32_t v = *(const uint32_t*)(Ktp + (size_t)d * 512 + 2 * tid);
        float qv = sh.a.qs[d];
        s0 += qv * bfbits2f(v << 16);
        s1 += qv * bfbits2f(v & 0xffff0000u);
      }
      float m = fmaxf(s0, s1);
      for (int off = 32; off > 0; off >>= 1) m = fmaxf(m, __shfl_down(m, off));
      if (lane == 0) sh.a.red[wid] = m;
      __syncthreads();
      if (tid == 0) sh.a.red[8] = fmaxf(fmaxf(sh.a.red[0], sh.a.red[1]), fmaxf(sh.a.red[2], sh.a.red[3]));
      __syncthreads();
      float mx = sh.a.red[8];
      float e0 = __expf(s0 - mx), e1 = __expf(s1 - mx);
      float ps = e0 + e1;
      for (int off = 32; off > 0; off >>= 1) ps += __shfl_down(ps, off);
      if (lane == 0) sh.a.red[4 + wid] = ps;
      __syncthreads();
      if (tid == 0) sh.a.red[9] = 1.f / (sh.a.red[4] + sh.a.red[5] + sh.a.red[6] + sh.a.red[7]);
      __syncthreads();
      float inv = sh.a.red[9];
      float a0 = e0 * inv, a1 = e1 * inv;
      float2 st = {a0, a1};
      *(float2*)&sh.a.sc[2 * tid] = st;
      float* aout = out_attn + ((size_t)bx * HOR_ + t) * 512;
      *(float2*)&aout[2 * tid] = st;
      __syncthreads();

      // PV
      const u16* Vp = Vb + (size_t)bx * (512 * 64);
      const int part = wid;
      const int dg = lane & 31, lh = lane >> 5;
      const int d = dg * 2;
      float c0a = 0.f, c1a = 0.f;
      const u16* vp = Vp + (size_t)(part * 128 + lh) * 64 + d;
      #pragma unroll 8
      for (int i = 0; i < 64; i++){
        int l = part * 128 + i * 2 + lh;
        uint32_t v = *(const uint32_t*)(vp + (size_t)i * 128);
        float w = sh.a.sc[l];
        c0a += w * bfbits2f(v << 16);
        c1a += w * bfbits2f(v & 0xffff0000u);
      }
      c0a += __shfl_xor(c0a, 32);
      c1a += __shfl_xor(c1a, 32);
      if (lh == 0){ sh.a.ctxp[part][d] = c0a; sh.a.ctxp[part][d + 1] = c1a; }
      __syncthreads();
      if (tid < 64)
        sh.a.ctxc[tid] = sh.a.ctxp[0][tid] + sh.a.ctxp[1][tid] + sh.a.ctxp[2][tid] + sh.a.ctxp[3][tid];
      __syncthreads();
      // pred partial: pp[p] = sum_{dd<64} ctxc[dd] * Mt[(nh*64+dd)*64 + p]
      {
        const int p = tid & 63, dp = tid >> 6;
        float acc = 0.f;
        const float* mp = Mt + (size_t)(nh * 64 + dp * 16) * 64 + p;
        const float* cp = &sh.a.ctxc[dp * 16];
        #pragma unroll
        for (int q2 = 0; q2 < 16; q2++)
          acc += cp[q2] * mp[(size_t)q2 * 64];
        sh.a.predred[dp][p] = acc;
      }
      __syncthreads();
      if (tid < 64)
        predpart[((size_t)(b * 8 + nh)) * 64 + tid] =
          sh.a.predred[0][tid] + sh.a.predred[1][tid] + sh.a.predred[2][tid] + sh.a.predred[3][tid];
    }
    gridbar(bar, xcd, ++ph);
  }

  // ---- tail: write pred for t=23 ----
  if (bid < 128 && tid < 64){
    const int b = bid, p = tid;
    float s = bcomb[p];
    const float* ppp = &predpart[((size_t)b * 8) * 64 + p];
    #pragma unroll
    for (int nh2 = 0; nh2 < 8; nh2++) s += ppp[nh2 * 64];
    out_pred[(size_t)b * (HOR_ * OUT_) + 23 * 64 + p] = s;
  }
}

// ---------------- host launcher ----------------

extern "C" void kernel_launch(void* const* d_in, const int* in_sizes, int n_in,
                              void* d_out, int out_size, void* d_ws, size_t ws_size,
                              hipStream_t stream){
  const float* enc  = (const float*)d_in[0];
  const float* h0   = (const float*)d_in[1];
  const float* c0   = (const float*)d_in[2];
  const float* dec  = (const float*)d_in[3];
  const float* W_ih = (const float*)d_in[4];
  const float* W_hh = (const float*)d_in[5];
  const float* b_ih = (const float*)d_in[6];
  const float* b_hh = (const float*)d_in[7];
  const float* Wq   = (const float*)d_in[8];
  const float* bq   = (const float*)d_in[9];
  const float* Wk   = (const float*)d_in[10];
  const float* bk   = (const float*)d_in[11];
  const float* Wv   = (const float*)d_in[12];
  const float* bv   = (const float*)d_in[13];
  const float* Wo   = (const float*)d_in[14];
  const float* bo   = (const float*)d_in[15];
  const float* Wfc  = (const float*)d_in[16];
  const float* bfc  = (const float*)d_in[17];
  float* out = (float*)d_out;

  char* ws = (char*)d_ws;
  size_t off = 0;
  auto alloc = [&](size_t bytes){ void* p = ws + off; off += (bytes + 255) & ~(size_t)255; return p; };
  u16*   Xb    = (u16*)  alloc((size_t)B_ * L_ * H_ * 2);
  u16*   Kt    = (u16*)  alloc((size_t)B_ * NH_ * HD_ * L_ * 2);
  u16*   Vb    = (u16*)  alloc((size_t)B_ * NH_ * L_ * HD_ * 2);
  u16*   Wkv   = (u16*)  alloc((size_t)1024 * 512 * 2);
  float* Wt4   = (float*)alloc((size_t)KCAT * G4H * 4);
  float* Wqt   = (float*)alloc((size_t)512 * 512 * 4);
  float* Mt    = (float*)alloc((size_t)512 * 64 * 4);
  float* bcomb = (float*)alloc(64 * 4);
  float* bias4 = (float*)alloc((size_t)G4H * 4);
  float* hb0   = (float*)alloc((size_t)B_ * H_ * 4);
  float* hb1   = (float*)alloc((size_t)B_ * H_ * 4);
  float* cbuf  = (float*)alloc((size_t)B_ * H_ * 4);
  float* qbuf  = (float*)alloc((size_t)B_ * H_ * 4);
  float* ppart = (float*)alloc((size_t)B_ * NH_ * OUT_ * 4);
  uint32_t* bar = (uint32_t*)alloc(4096);
  if (off > ws_size){
    fprintf(stderr, "WORKSPACE TOO SMALL: need %zu, have %zu\n", off, ws_size);
  }

  float* out_pred = out;                                 // (B, HOR, OUT)
  float* out_attn = out + (size_t)B_ * HOR_ * OUT_;      // (B, NH, HOR, L)

  k_convert_x<<<4096, 256, 0, stream>>>((const float4*)enc, (ushort4*)Xb, (B_ * L_ * H_) / 4);
  k_prep<<<8586, 256, 0, stream>>>(Wk, Wv, W_ih, W_hh, b_ih, b_hh, Wq, Wfc, Wo, bo, bfc,
                                   dec, h0, c0, Wkv, Wt4, Wqt, bias4, Mt, bcomb,
                                   ppart, hb0, cbuf, bar);
  k_gemm_kv<<<dim3(8, 512), 256, 0, stream>>>(Xb, Wkv, bk, bv, Kt, Vb);

  k_loop<<<512, 256, 0, stream>>>(hb0, hb1, cbuf, (const float4*)Wt4, (const float4*)bias4,
                                  Wqt, bq, Kt, Vb, Mt, bcomb, qbuf, ppart, bar,
                                  out_pred, out_attn);
}